// Round 2
// baseline (375.299 us; speedup 1.0000x reference)
//
#include <hip/hip_runtime.h>
#include <hip/hip_bf16.h>
#include <math.h>

#define B_ROWS 131072
#define NMODS 6
#define NPREDS 30

// 12 accumulators in d_ws:
// 0 ade6x, 1 ade6y, 2 fde6x, 3 fde6y, 4 ade1x, 5 ade1y, 6 fde1x, 7 fde1y,
// 8 regloss, 9 summgn, 10 numcls, 11 numreg

__device__ __forceinline__ float wave_reduce(float v) {
    v += __shfl_xor(v, 32);
    v += __shfl_xor(v, 16);
    v += __shfl_xor(v, 8);
    v += __shfl_xor(v, 4);
    v += __shfl_xor(v, 2);
    v += __shfl_xor(v, 1);
    return v;
}

__global__ __launch_bounds__(256) void loss_main(
    const float* __restrict__ reg,   // [B,6,30,2]
    const float* __restrict__ cls,   // [B,6]
    const float* __restrict__ gt,    // [B,30,2]
    const int* __restrict__ has,     // [B,30] (bool widened to int32 by harness)
    float* __restrict__ acc)
{
    const int lane = threadIdx.x & 63;
    const int wid  = threadIdx.x >> 6;
    const int gw   = blockIdx.x * 4 + wid;
    const int nw   = gridDim.x * 4;

    float ade6x = 0.f, ade6y = 0.f, fde6x = 0.f, fde6y = 0.f;
    float ade1x = 0.f, ade1y = 0.f, fde1x = 0.f, fde1y = 0.f;
    float regloss = 0.f, summgn = 0.f, numcls = 0.f, numreg = 0.f;

    for (int b = gw; b < B_ROWS; b += nw) {
        // ---- has -> last_idx, valid ----
        bool hp = false;
        if (lane < NPREDS) hp = (has[b * NPREDS + lane] != 0);
        unsigned long long mask = __ballot(hp);
        int last_idx = mask ? (63 - __builtin_clzll(mask)) : (NPREDS - 1);
        bool valid = (mask & ~1ull) != 0ull;   // max(has + 0.1*t/30) > 1.0

        // ---- gt row (lane t holds gt[b,t,:]) ----
        float gx = 0.f, gy = 0.f;
        if (lane < NPREDS) {
            const float2 g = ((const float2*)gt)[b * NPREDS + lane];
            gx = g.x; gy = g.y;
        }

        // ---- heading: seg[t] = atan2(gt[t+1]-gt[t]), t in [0,28] ----
        float gxn = __shfl(gx, (lane + 1) & 63);
        float gyn = __shfl(gy, (lane + 1) & 63);
        float seg = 0.f;
        if (lane < NPREDS - 1) seg = atan2f(gyn - gy, gxn - gx);
        float segp  = __shfl(seg, (lane + 63) & 63);   // seg[t-1]
        float seg28 = __shfl(seg, NPREDS - 2);

        float gx0  = __shfl(gx, 0),          gy0  = __shfl(gy, 0);
        float gx29 = __shfl(gx, NPREDS - 1), gy29 = __shfl(gy, NPREDS - 1);
        float mdx = gx0 - gx29, mdy = gy0 - gy29;
        bool moving = (mdx * mdx + mdy * mdy) > 4.0f;

        float head;  // radians (deg round-trip in ref is identity up to fp eps)
        if (lane == 0)                head = seg;
        else if (lane >= NPREDS - 1)  head = seg28;
        else                          head = (seg == 0.f || segp == 0.f)
                                             ? (seg + segp) : 0.5f * (seg + segp);
        if (!moving) head = 0.f;
        float ct = cosf(-head);
        float st = sinf(-head);

        // ---- per-mode dist at last_idx (lanes 0..5) ----
        float glx = __shfl(gx, last_idx);
        float gly = __shfl(gy, last_idx);
        float d = 0.f;
        if (lane < NMODS) {
            const float2 rl = ((const float2*)reg)[(size_t)(b * NMODS + lane) * NPREDS + last_idx];
            float dxm = rl.x - glx, dym = rl.y - gly;
            d = sqrtf(dxm * dxm + dym * dym);
        }
        float d0 = __shfl(d, 0), d1 = __shfl(d, 1), d2 = __shfl(d, 2);
        float d3 = __shfl(d, 3), d4 = __shfl(d, 4), d5 = __shfl(d, 5);
        float mind = d0; int mini = 0;
        if (d1 < mind) { mind = d1; mini = 1; }
        if (d2 < mind) { mind = d2; mini = 2; }
        if (d3 < mind) { mind = d3; mini = 3; }
        if (d4 < mind) { mind = d4; mini = 4; }
        if (d5 < mind) { mind = d5; mini = 5; }

        // ---- cls margin loss terms (lanes 0..5) ----
        float cm = (lane < NMODS) ? cls[b * NMODS + lane] : 0.f;
        float clsmin = __shfl(cm, mini);
        if (lane < NMODS) {
            float mgn = clsmin - cm;
            if (valid && (mind < 2.0f) && ((d - mind) > 0.2f) && (mgn < 0.2f)) {
                numcls += 1.0f;
                summgn += mgn;
            }
        }

        // ---- top1 = argmax cls (first occurrence) ----
        float c0 = __shfl(cm, 0), c1 = __shfl(cm, 1), c2 = __shfl(cm, 2);
        float c3 = __shfl(cm, 3), c4 = __shfl(cm, 4), c5 = __shfl(cm, 5);
        float bestc = c0; int top1 = 0;
        if (c1 > bestc) { bestc = c1; top1 = 1; }
        if (c2 > bestc) { bestc = c2; top1 = 2; }
        if (c3 > bestc) { bestc = c3; top1 = 3; }
        if (c4 > bestc) { bestc = c4; top1 = 4; }
        if (c5 > bestc) { bestc = c5; top1 = 5; }

        // ---- num_reg ----
        if (lane == 0 && valid) numreg += (float)__builtin_popcountll(mask);

        // ---- main loop over (m,t) pairs, coalesced float2 loads ----
        const float2* regrow = ((const float2*)reg) + (size_t)b * (NMODS * NPREDS);
        #pragma unroll
        for (int it = 0; it < 3; ++it) {
            int p = lane + it * 64;
            // shuffles executed by all lanes (t clamped), results masked below
            int m = p / NPREDS;
            int t = p - m * NPREDS;
            int ts = (p < NMODS * NPREDS) ? t : 0;
            float gxt = __shfl(gx, ts);
            float gyt = __shfl(gy, ts);
            float ctt = __shfl(ct, ts);
            float stt = __shfl(st, ts);
            if (p < NMODS * NPREDS) {
                float2 rv = regrow[p];
                float dx = fabsf(gxt - rv.x);
                float dy = fabsf(gyt - rv.y);
                float ax = fabsf(ctt * dx - stt * dy);
                float ay = fabsf(stt * dx + ctt * dy);
                ade6x += ax; ade6y += ay;
                if (t == NPREDS - 1) { fde6x += ax; fde6y += ay; }
                if (m == top1) {
                    ade1x += ax; ade1y += ay;
                    if (t == NPREDS - 1) { fde1x += ax; fde1y += ay; }
                }
                if (m == mini && valid && ((mask >> t) & 1ull)) {
                    float e0 = rv.x - gxt;
                    float e1 = rv.y - gyt;
                    float a0 = fabsf(e0), a1 = fabsf(e1);
                    regloss += (a0 < 1.f) ? (0.5f * e0 * e0) : (a0 - 0.5f);
                    regloss += (a1 < 1.f) ? (0.5f * e1 * e1) : (a1 - 0.5f);
                }
            }
        }
    }

    // ---- wave reduce -> block reduce -> one atomic per block per acc ----
    float vals[12] = { ade6x, ade6y, fde6x, fde6y, ade1x, ade1y, fde1x, fde1y,
                       regloss, summgn, numcls, numreg };
    #pragma unroll
    for (int i = 0; i < 12; ++i) vals[i] = wave_reduce(vals[i]);

    __shared__ float blk[4][12];
    if (lane == 0) {
        #pragma unroll
        for (int i = 0; i < 12; ++i) blk[wid][i] = vals[i];
    }
    __syncthreads();
    if (threadIdx.x < 12) {
        float s = blk[0][threadIdx.x] + blk[1][threadIdx.x]
                + blk[2][threadIdx.x] + blk[3][threadIdx.x];
        atomicAdd(&acc[threadIdx.x], s);
    }
}

__global__ void finalize(const float* __restrict__ acc, float* __restrict__ out) {
    if (threadIdx.x == 0) {
        float nc = acc[10], nr = acc[11];
        float cls_loss = 0.2f * nc - acc[9];      // CLS_COEF * (MGN*num_cls - sum_mgn)
        float reg_loss = acc[8];                  // REG_COEF
        float loss = cls_loss / (nc + 1e-10f) + reg_loss / (nr + 1e-10f);
        out[0]  = loss;
        out[1]  = cls_loss;
        out[2]  = nc;
        out[3]  = reg_loss;
        out[4]  = nr;
        out[5]  = acc[0];   // ade6_x
        out[6]  = acc[1];   // ade6_y
        out[7]  = acc[2];   // fde6_x
        out[8]  = acc[3];   // fde6_y
        out[9]  = 23592960.0f;   // 6*B*30
        out[10] = 786432.0f;     // 6*B
        out[11] = acc[4];   // ade1_x
        out[12] = acc[5];   // ade1_y
        out[13] = acc[6];   // fde1_x
        out[14] = acc[7];   // fde1_y
        out[15] = 3932160.0f;    // B*30
        out[16] = 131072.0f;     // B
    }
}

extern "C" void kernel_launch(void* const* d_in, const int* in_sizes, int n_in,
                              void* d_out, int out_size, void* d_ws, size_t ws_size,
                              hipStream_t stream) {
    const float* reg = (const float*)d_in[0];
    const float* cls = (const float*)d_in[1];
    const float* gt  = (const float*)d_in[2];
    const int*   has = (const int*)d_in[3];
    float* out = (float*)d_out;
    float* acc = (float*)d_ws;

    hipMemsetAsync(acc, 0, 12 * sizeof(float), stream);
    loss_main<<<2048, 256, 0, stream>>>(reg, cls, gt, has, acc);
    finalize<<<1, 64, 0, stream>>>(acc, out);
}